// Round 13
// baseline (322.629 us; speedup 1.0000x reference)
//
#include <hip/hip_runtime.h>
#include <hip/hip_bf16.h>

typedef __attribute__((ext_vector_type(8))) short bf16x8;
typedef __attribute__((ext_vector_type(4))) float f32x4;
typedef __attribute__((ext_vector_type(4))) unsigned int u32x4;
typedef __attribute__((ext_vector_type(2))) unsigned int u32x2;

#define B_SZ 4
#define C_SZ 256
#define N_SZ 4096
#define DK_SZ 32

// ws layout in bf16 elements
#define WQB_OFF 0
#define WKB_OFF 8192
#define WVB_OFF 16384
#define QB_OFF  81920
#define KB_OFF  606208
#define VB_OFF  1130496   // V tiled: [b][mblk=n/64][c][64]

__device__ __forceinline__ short f2bf(float f) {
    union { float f; unsigned int u; } v; v.f = f;
    unsigned int r = v.u + 0x7fffu + ((v.u >> 16) & 1u);
    return (short)(r >> 16);
}

__device__ __forceinline__ float asf(unsigned int u) {
    union { unsigned int u; float f; } v; v.u = u;
    return v.f;
}

__device__ __forceinline__ unsigned int cvt_pk_bf16(float lo, float hi) {
    unsigned int r;
    asm volatile("v_cvt_pk_bf16_f32 %0, %1, %2" : "=v"(r) : "v"(lo), "v"(hi));
    return r;
}

__device__ __forceinline__ f32x4 mfma16(bf16x8 a, bf16x8 b, f32x4 c) {
    return __builtin_amdgcn_mfma_f32_16x16x32_bf16(a, b, c, 0, 0, 0);
}

// XCD-affinity remap (k_prep, grid 256): batch b owns XCDs {2b, 2b+1}.
__device__ __forceinline__ void remap_block(int i, int& b, int& n0) {
    b = (i & 7) >> 1;
    n0 = (((i >> 3) << 1) | (i & 1)) * 64;
}

// ---------------- weight conversion ----------------
__global__ __launch_bounds__(256) void k_convw(const float* __restrict__ Wq,
                                               const float* __restrict__ Wk,
                                               const float* __restrict__ Wv,
                                               short* __restrict__ ws) {
    int i = blockIdx.x * 256 + threadIdx.x;
    if (i < 8192) {
        ws[WQB_OFF + i] = f2bf(Wq[i]);
        ws[WKB_OFF + i] = f2bf(Wk[i]);
    }
    ws[WVB_OFF + i] = f2bf(Wv[i]);
}

// ---------------- projection: q, k as [b][n][32] bf16; v TILED [b][mblk][c][64] ----------------
__global__ __launch_bounds__(256) void k_prep(const float* __restrict__ x,
                                              const float* __restrict__ bq,
                                              const float* __restrict__ bk,
                                              const float* __restrict__ bv,
                                              short* __restrict__ ws) {
    __shared__ short xsT[64][264];
    __shared__ short vt_s[64][258];

    int b, n0;
    remap_block(blockIdx.x, b, n0);
    const int t = threadIdx.x;
    const float* xb = x + (size_t)b * C_SZ * N_SZ;

    {
        int c0 = t >> 4, n4 = (t & 15) * 4;
#pragma unroll
        for (int i = 0; i < 16; i++) {
            int c = c0 + 16 * i;
            float4 v = *(const float4*)(xb + (size_t)c * N_SZ + n0 + n4);
            xsT[n4 + 0][c] = f2bf(v.x);
            xsT[n4 + 1][c] = f2bf(v.y);
            xsT[n4 + 2][c] = f2bf(v.z);
            xsT[n4 + 3][c] = f2bf(v.w);
        }
    }
    __syncthreads();

    const int w = t >> 6, l = t & 63;
    const int lr = l & 15, lk = l >> 4;

    bf16x8 af[8];
#pragma unroll
    for (int kk = 0; kk < 8; kk++)
        af[kk] = *(const bf16x8*)(&xsT[w * 16 + lr][kk * 32 + lk * 8]);

#pragma unroll
    for (int qk = 0; qk < 2; qk++) {
        const short* wb = ws + (qk ? WKB_OFF : WQB_OFF);
        const float* bias = qk ? bk : bq;
        short* outp = ws + (qk ? KB_OFF : QB_OFF) + (size_t)b * N_SZ * DK_SZ;
#pragma unroll
        for (int cf = 0; cf < 2; cf++) {
            f32x4 acc = {0.f, 0.f, 0.f, 0.f};
#pragma unroll
            for (int kk = 0; kk < 8; kk++) {
                bf16x8 bfr = *(const bf16x8*)(wb + (cf * 16 + lr) * 256 + kk * 32 + lk * 8);
                acc = mfma16(af[kk], bfr, acc);
            }
            float bias_v = bias[cf * 16 + lr];
#pragma unroll
            for (int r = 0; r < 4; r++) {
                int row = w * 16 + lk * 4 + r;
                outp[(size_t)(n0 + row) * DK_SZ + cf * 16 + lr] = f2bf(acc[r] + bias_v);
            }
        }
    }

#pragma unroll
    for (int cf = 0; cf < 16; cf++) {
        f32x4 acc = {0.f, 0.f, 0.f, 0.f};
#pragma unroll
        for (int kk = 0; kk < 8; kk++) {
            bf16x8 bfr = *(const bf16x8*)(ws + WVB_OFF + (cf * 16 + lr) * 256 + kk * 32 + lk * 8);
            acc = mfma16(af[kk], bfr, acc);
        }
        float bias_v = bv[cf * 16 + lr];
#pragma unroll
        for (int r = 0; r < 4; r++) {
            vt_s[w * 16 + lk * 4 + r][cf * 16 + lr] = f2bf(acc[r] + bias_v);
        }
    }
    __syncthreads();
    {
        short* vt = ws + VB_OFF + (size_t)b * C_SZ * N_SZ + (size_t)(n0 >> 6) * (C_SZ * 64);
        int nn = t & 63;
#pragma unroll
        for (int i = 0; i < 64; i++) {
            int c = (t >> 6) + 4 * i;
            vt[c * 64 + nn] = vt_s[nn][c];
        }
    }
}

// ---------------- k_mix: heterogeneous blocks (compute | attention-writer) ----------------
// Grid 1536 x 512 thr, 34 KB LDS, 4 blocks/CU -> each CU runs a mix.
// Index math keeps XCD-batch affinity (x = i&7, b = x>>1) and partitions:
//   attnc  (q%3 == (1+x)%3): 512 blocks, 32-row n-tiles -> rowsums + PV + residual
//   expand (else):          1024 blocks, 16-row n-tiles -> self rowsum + register-P
//                            attention writer, 8 back-to-back nt stores per burst
__global__ __launch_bounds__(512, 4) void k_mix(short* __restrict__ ws,
                                                const float* __restrict__ x,
                                                const float* __restrict__ gamma_p,
                                                float* __restrict__ out) {
    __shared__ __align__(16) char smem[34816];

    const int i = blockIdx.x;
    const int xcd = i & 7;
    const int q = i >> 3;                 // 0..191
    const int qb = (1 + xcd) % 3;         // attnc residue
    const int b = xcd >> 1;

    const int t = threadIdx.x, w = t >> 6, l = t & 63;
    const int lr = l & 15, lk = l >> 4;

    const short* qbuf = ws + QB_OFF + (size_t)b * N_SZ * DK_SZ;
    const short* kb = ws + KB_OFF + (size_t)b * N_SZ * DK_SZ;
    float* attn_b = out + (size_t)B_SZ * C_SZ * N_SZ + (size_t)b * N_SZ * N_SZ;

    if (q % 3 == qb) {
        // ================= attnc path (r12 k_attnc) =================
        short (*p_lds)[32][72] = (short(*)[32][72])smem;
        float* rsum_s = (float*)(smem + 9216);
        const int n0 = 32 * ((q / 3) + 64 * (xcd & 1));

        const int ng = w & 1, mq = w >> 1;
        const int cq = w & 3, mh = w >> 2;
        const short* vb2 = ws + VB_OFF + (size_t)b * C_SZ * N_SZ;

        bf16x8 qf = *(const bf16x8*)(qbuf + (size_t)(n0 + ng * 16 + lr) * DK_SZ + lk * 8);

        float rs = 0.f;
        for (int mt = 0; mt < 16; mt++) {
            int mb = mq * 1024 + mt * 64;
            bf16x8 kfa = *(const bf16x8*)(kb + (size_t)(mb + lr) * DK_SZ + lk * 8);
            bf16x8 kfb = *(const bf16x8*)(kb + (size_t)(mb + 16 + lr) * DK_SZ + lk * 8);
            bf16x8 kfc = *(const bf16x8*)(kb + (size_t)(mb + 32 + lr) * DK_SZ + lk * 8);
            bf16x8 kfd = *(const bf16x8*)(kb + (size_t)(mb + 48 + lr) * DK_SZ + lk * 8);
            f32x4 s0 = mfma16(kfa, qf, (f32x4){0.f, 0.f, 0.f, 0.f});
            f32x4 s1 = mfma16(kfb, qf, (f32x4){0.f, 0.f, 0.f, 0.f});
            f32x4 s2 = mfma16(kfc, qf, (f32x4){0.f, 0.f, 0.f, 0.f});
            f32x4 s3 = mfma16(kfd, qf, (f32x4){0.f, 0.f, 0.f, 0.f});
#pragma unroll
            for (int r = 0; r < 4; r++)
                rs += __expf(s0[r]) + __expf(s1[r]) + __expf(s2[r]) + __expf(s3[r]);
        }
        rs += __shfl_xor(rs, 16);
        rs += __shfl_xor(rs, 32);
        if (l < 16) rsum_s[mq * 32 + ng * 16 + l] = rs;
        __syncthreads();
        const float invp = 1.f / (rsum_s[ng * 16 + lr] + rsum_s[32 + ng * 16 + lr] +
                                  rsum_s[64 + ng * 16 + lr] + rsum_s[96 + ng * 16 + lr]);

        f32x4 O[4][2];
#pragma unroll
        for (int cf = 0; cf < 4; cf++)
#pragma unroll
            for (int rgi = 0; rgi < 2; rgi++) O[cf][rgi] = (f32x4){0.f, 0.f, 0.f, 0.f};

#define SCOMP(tt, pb)                                                               \
    {                                                                               \
        bf16x8 kf = *(const bf16x8*)(kb + (size_t)((tt) * 64 + mq * 16 + lr) * DK_SZ + lk * 8); \
        f32x4 s = mfma16(kf, qf, (f32x4){0.f, 0.f, 0.f, 0.f});                      \
        u32x2 pk;                                                                   \
        pk[0] = cvt_pk_bf16(__expf(s[0]) * invp, __expf(s[1]) * invp);              \
        pk[1] = cvt_pk_bf16(__expf(s[2]) * invp, __expf(s[3]) * invp);              \
        *(u32x2*)(&p_lds[pb][ng * 16 + lr][mq * 16 + lk * 4]) = pk;                 \
    }

#define PVOP(tt, pb)                                                                \
    {                                                                               \
        bf16x8 Bf[2], Af[4];                                                        \
        _Pragma("unroll")                                                           \
        for (int rgi = 0; rgi < 2; rgi++)                                           \
            Bf[rgi] = *(const bf16x8*)((const char*)&p_lds[pb][rgi * 16 + lr][0]    \
                                       + mh * 64 + lk * 16);                        \
        const short* vt = vb2 + (size_t)(tt) * (C_SZ * 64);                         \
        _Pragma("unroll")                                                           \
        for (int cf = 0; cf < 4; cf++)                                              \
            Af[cf] = *(const bf16x8*)(vt + (cq * 64 + cf * 16 + lr) * 64            \
                                      + mh * 32 + lk * 8);                          \
        _Pragma("unroll")                                                           \
        for (int cf = 0; cf < 4; cf++)                                              \
            _Pragma("unroll")                                                       \
            for (int rgi = 0; rgi < 2; rgi++)                                       \
                O[cf][rgi] = mfma16(Af[cf], Bf[rgi], O[cf][rgi]);                   \
    }

        SCOMP(0, 0);
        for (int mt = 0; mt < 64; mt++) {
            __syncthreads();
            const int cur = mt & 1;
            if (mt < 63) SCOMP(mt + 1, cur ^ 1);
            PVOP(mt, cur);
        }
#undef SCOMP
#undef PVOP

        __syncthreads();
        float* o_red = (float*)smem;
        if (mh == 1) {
#pragma unroll
            for (int cf = 0; cf < 4; cf++)
#pragma unroll
                for (int rgi = 0; rgi < 2; rgi++)
#pragma unroll
                    for (int r = 0; r < 4; r++)
                        o_red[(cq * 64 + cf * 16 + 4 * lk + r) * 33 + rgi * 16 + lr] = O[cf][rgi][r];
        }
        __syncthreads();
        if (mh == 0) {
#pragma unroll
            for (int cf = 0; cf < 4; cf++)
#pragma unroll
                for (int rgi = 0; rgi < 2; rgi++)
#pragma unroll
                    for (int r = 0; r < 4; r++)
                        o_red[(cq * 64 + cf * 16 + 4 * lk + r) * 33 + rgi * 16 + lr] += O[cf][rgi][r];
        }
        __syncthreads();
        {
            const float g = gamma_p[0];
            const float* xb = x + (size_t)b * C_SZ * N_SZ;
            float* ob = out + (size_t)b * C_SZ * N_SZ;
            int nn = t & 31;
            int c0 = t >> 5;
#pragma unroll
            for (int i2 = 0; i2 < 16; i2++) {
                int c = c0 + 16 * i2;
                size_t idx = (size_t)c * N_SZ + n0 + nn;
                ob[idx] = g * o_red[c * 33 + nn] + xb[idx];
            }
        }
    } else {
        // ================= expand path: attention writer =================
        // rank within this XCD's expand blocks
        const int bad = qb;                       // excluded q%3 residue
        const int a1 = (bad == 2) ? 1 : 2;        // larger allowed residue
        const int f = 2 * (q / 3) + ((q % 3) == a1 ? 1 : 0);   // 0..127
        const int n0 = 16 * (f + 128 * (xcd & 1));

        float* rsum_e = (float*)smem;             // [8][16]
        bf16x8 qf = *(const bf16x8*)(qbuf + (size_t)(n0 + lr) * DK_SZ + lk * 8);

        // pass 1: rowsum over wave stripe m in [w*512, w*512+512)
        float rs = 0.f;
        for (int st = 0; st < 32; st++) {
            const int mb = w * 512 + st * 16;
            bf16x8 kf = *(const bf16x8*)(kb + (size_t)(mb + lr) * DK_SZ + lk * 8);
            f32x4 s = mfma16(kf, qf, (f32x4){0.f, 0.f, 0.f, 0.f});
            rs += __expf(s[0]) + __expf(s[1]) + __expf(s[2]) + __expf(s[3]);
        }
        rs += __shfl_xor(rs, 16);
        rs += __shfl_xor(rs, 32);
        if (l < 16) rsum_e[w * 16 + l] = rs;
        __syncthreads();
        float tot = 0.f;
#pragma unroll
        for (int ww = 0; ww < 8; ww++) tot += rsum_e[ww * 16 + lr];
        const float invs = 1.f / tot;

        // pass 2: recompute S, P in registers, 8 back-to-back nt stores per burst
        float* arow = attn_b + (size_t)(n0 + lr) * N_SZ;
#pragma unroll
        for (int burst = 0; burst < 4; burst++) {
            f32x4 e[8];
#pragma unroll
            for (int t8 = 0; t8 < 8; t8++) {
                const int mb = w * 512 + burst * 128 + t8 * 16;
                bf16x8 kf = *(const bf16x8*)(kb + (size_t)(mb + lr) * DK_SZ + lk * 8);
                f32x4 s = mfma16(kf, qf, (f32x4){0.f, 0.f, 0.f, 0.f});
                e[t8][0] = __expf(s[0]) * invs;
                e[t8][1] = __expf(s[1]) * invs;
                e[t8][2] = __expf(s[2]) * invs;
                e[t8][3] = __expf(s[3]) * invs;
            }
#pragma unroll
            for (int t8 = 0; t8 < 8; t8++) {
                __builtin_nontemporal_store(e[t8],
                    (f32x4*)(arow + w * 512 + burst * 128 + t8 * 16 + lk * 4));
            }
        }
    }
}

extern "C" void kernel_launch(void* const* d_in, const int* in_sizes, int n_in,
                              void* d_out, int out_size, void* d_ws, size_t ws_size,
                              hipStream_t stream) {
    const float* x     = (const float*)d_in[0];
    const float* Wq    = (const float*)d_in[1];
    const float* bq    = (const float*)d_in[2];
    const float* Wk    = (const float*)d_in[3];
    const float* bk    = (const float*)d_in[4];
    const float* Wv    = (const float*)d_in[5];
    const float* bv    = (const float*)d_in[6];
    const float* gamma = (const float*)d_in[7];
    short* ws = (short*)d_ws;
    float* out = (float*)d_out;

    hipLaunchKernelGGL(k_convw, dim3(256), dim3(256), 0, stream, Wq, Wk, Wv, ws);
    hipLaunchKernelGGL(k_prep, dim3(256), dim3(256), 0, stream, x, bq, bk, bv, ws);
    hipLaunchKernelGGL(k_mix, dim3(1536), dim3(512), 0, stream, ws, x, gamma, out);
}

// Round 14
// 137.994 us; speedup vs baseline: 2.3380x; 2.3380x over previous
//
#include <hip/hip_runtime.h>
#include <hip/hip_bf16.h>

typedef __attribute__((ext_vector_type(8))) short bf16x8;
typedef __attribute__((ext_vector_type(4))) float f32x4;
typedef __attribute__((ext_vector_type(4))) unsigned int u32x4;
typedef __attribute__((ext_vector_type(2))) unsigned int u32x2;

#define B_SZ 4
#define C_SZ 256
#define N_SZ 4096
#define DK_SZ 32

// ws layout in bf16 elements
#define WQB_OFF 0
#define WKB_OFF 8192
#define WVB_OFF 16384
#define QB_OFF  81920
#define KB_OFF  606208
#define VB_OFF  1130496

__device__ __forceinline__ short f2bf(float f) {
    union { float f; unsigned int u; } v; v.f = f;
    unsigned int r = v.u + 0x7fffu + ((v.u >> 16) & 1u);
    return (short)(r >> 16);
}

__device__ __forceinline__ float asf(unsigned int u) {
    union { unsigned int u; float f; } v; v.u = u;
    return v.f;
}

__device__ __forceinline__ unsigned int cvt_pk_bf16(float lo, float hi) {
    unsigned int r;
    asm volatile("v_cvt_pk_bf16_f32 %0, %1, %2" : "=v"(r) : "v"(lo), "v"(hi));
    return r;
}

__device__ __forceinline__ f32x4 mfma16(bf16x8 a, bf16x8 b, f32x4 c) {
    return __builtin_amdgcn_mfma_f32_16x16x32_bf16(a, b, c, 0, 0, 0);
}

__device__ __forceinline__ void gload_lds16(const void* g, void* l) {
    __builtin_amdgcn_global_load_lds((const __attribute__((address_space(1))) unsigned int*)g,
                                     (__attribute__((address_space(3))) unsigned int*)l, 16, 0, 0);
}

// XCD-affinity remap: grid = 256 1D, block i -> XCD i%8 (round-robin).
// Batch b owns XCDs {2b, 2b+1} -> per-XCD working set (V_b 2MB + K_b + Q_b) < 4MB L2.
__device__ __forceinline__ void remap_block(int i, int& b, int& n0) {
    b = (i & 7) >> 1;
    n0 = (((i >> 3) << 1) | (i & 1)) * 64;
}

// ---------------- weight conversion ----------------
__global__ __launch_bounds__(256) void k_convw(const float* __restrict__ Wq,
                                               const float* __restrict__ Wk,
                                               const float* __restrict__ Wv,
                                               short* __restrict__ ws) {
    int i = blockIdx.x * 256 + threadIdx.x;
    if (i < 8192) {
        ws[WQB_OFF + i] = f2bf(Wq[i]);
        ws[WKB_OFF + i] = f2bf(Wk[i]);
    }
    ws[WVB_OFF + i] = f2bf(Wv[i]);
}

// ---------------- projection: q, k as [b][n][32] bf16; v as [b][c][n] bf16 ----------------
__global__ __launch_bounds__(256) void k_prep(const float* __restrict__ x,
                                              const float* __restrict__ bq,
                                              const float* __restrict__ bk,
                                              const float* __restrict__ bv,
                                              short* __restrict__ ws) {
    __shared__ short xsT[64][264];
    __shared__ short vt_s[64][258];

    int b, n0;
    remap_block(blockIdx.x, b, n0);
    const int t = threadIdx.x;
    const float* xb = x + (size_t)b * C_SZ * N_SZ;

    {
        int c0 = t >> 4, n4 = (t & 15) * 4;
#pragma unroll
        for (int i = 0; i < 16; i++) {
            int c = c0 + 16 * i;
            float4 v = *(const float4*)(xb + (size_t)c * N_SZ + n0 + n4);
            xsT[n4 + 0][c] = f2bf(v.x);
            xsT[n4 + 1][c] = f2bf(v.y);
            xsT[n4 + 2][c] = f2bf(v.z);
            xsT[n4 + 3][c] = f2bf(v.w);
        }
    }
    __syncthreads();

    const int w = t >> 6, l = t & 63;
    const int lr = l & 15, lk = l >> 4;

    bf16x8 af[8];
#pragma unroll
    for (int kk = 0; kk < 8; kk++)
        af[kk] = *(const bf16x8*)(&xsT[w * 16 + lr][kk * 32 + lk * 8]);

#pragma unroll
    for (int qk = 0; qk < 2; qk++) {
        const short* wb = ws + (qk ? WKB_OFF : WQB_OFF);
        const float* bias = qk ? bk : bq;
        short* outp = ws + (qk ? KB_OFF : QB_OFF) + (size_t)b * N_SZ * DK_SZ;
#pragma unroll
        for (int cf = 0; cf < 2; cf++) {
            f32x4 acc = {0.f, 0.f, 0.f, 0.f};
#pragma unroll
            for (int kk = 0; kk < 8; kk++) {
                bf16x8 bfr = *(const bf16x8*)(wb + (cf * 16 + lr) * 256 + kk * 32 + lk * 8);
                acc = mfma16(af[kk], bfr, acc);
            }
            float bias_v = bias[cf * 16 + lr];
#pragma unroll
            for (int r = 0; r < 4; r++) {
                int row = w * 16 + lk * 4 + r;
                outp[(size_t)(n0 + row) * DK_SZ + cf * 16 + lr] = f2bf(acc[r] + bias_v);
            }
        }
    }

#pragma unroll
    for (int cf = 0; cf < 16; cf++) {
        f32x4 acc = {0.f, 0.f, 0.f, 0.f};
#pragma unroll
        for (int kk = 0; kk < 8; kk++) {
            bf16x8 bfr = *(const bf16x8*)(ws + WVB_OFF + (cf * 16 + lr) * 256 + kk * 32 + lk * 8);
            acc = mfma16(af[kk], bfr, acc);
        }
        float bias_v = bv[cf * 16 + lr];
#pragma unroll
        for (int r = 0; r < 4; r++) {
            vt_s[w * 16 + lk * 4 + r][cf * 16 + lr] = f2bf(acc[r] + bias_v);
        }
    }
    __syncthreads();
    {
        short* vb = ws + VB_OFF + (size_t)b * C_SZ * N_SZ;
        int nn = t & 63;
#pragma unroll
        for (int i = 0; i < 64; i++) {
            int c = (t >> 6) + 4 * i;
            vb[(size_t)c * N_SZ + n0 + nn] = vt_s[nn][c];
        }
    }
}

// ---------------- fused attention (r7 structure + full-line ASTORE from p_lds) ----------------
// 512 threads = 8 waves. SCOMP mapping: rg=w&3 (16 q-rows), ch=w>>2 (m-half).
// PV mapping:    cq=w&3 (64-channel quarter), mh=w>>2 (m-half) -> each V
// element read by exactly ONE wave. P through double-buffered LDS (8 KB/tile).
// Per iter (1 barrier): wait vmcnt(2)+lgkm(0); barrier; KREAD(t+1);
// SCOMP(t+1) [mfma, exp, cvt, P->p_lds[alt]]; STAGE(t+2) [5 gload_lds];
// ASTORE(t) [p_lds[cur] -> FULL-128B-LINE nt stores: 8 lanes x 16B/row];
// PV(t). vm order per iter: 5 loads then 2 stores -> vmcnt(2) retires exactly
// the staging loads; store acks ride ~1 iteration (r13 counters: full-line
// stores keep WRITE_SIZE at the 285 MB payload vs 388 MB for 64B segments).
__global__ __launch_bounds__(512, 1) void k_attn(const short* __restrict__ ws,
                                                 const float* __restrict__ x,
                                                 const float* __restrict__ gamma_p,
                                                 float* __restrict__ out) {
    __shared__ short v_lds[3][16384];   // V tiles [c][64] linear, slot^(c&7) swizzled; 96 KB
    __shared__ short k_lds[3][2304];    // K tiles [64][32], slot^((row>>1)&3) swizzled
    __shared__ short p_lds[2][64][72];  // P tiles [n][m], stride 144 B; 18.4 KB
    __shared__ float rsum_s[2][64];

    int b, n0;
    remap_block(blockIdx.x, b, n0);
    const int t = threadIdx.x, w = t >> 6, l = t & 63;
    const int rg = w & 3, ch = w >> 2;   // rg=cq for PV, ch=mh
    const int lr = l & 15, lk = l >> 4;

    const short* qb = ws + QB_OFF + (size_t)b * N_SZ * DK_SZ;
    const short* kb = ws + KB_OFF + (size_t)b * N_SZ * DK_SZ;
    const short* vb = ws + VB_OFF + (size_t)b * C_SZ * N_SZ;
    const char* kbb = (const char*)kb;

    bf16x8 qf = *(const bf16x8*)(qb + (size_t)(n0 + rg * 16 + lr) * DK_SZ + lk * 8);

    // ---- pass 1: rowsum of exp(S) over m-half ch, barrier-free ----
    float rs = 0.f;
    for (int mt = 0; mt < 32; mt++) {
        int mb = ch * 2048 + mt * 64;
        bf16x8 kfa = *(const bf16x8*)(kb + (size_t)(mb + lr) * DK_SZ + lk * 8);
        bf16x8 kfb = *(const bf16x8*)(kb + (size_t)(mb + 16 + lr) * DK_SZ + lk * 8);
        bf16x8 kfc = *(const bf16x8*)(kb + (size_t)(mb + 32 + lr) * DK_SZ + lk * 8);
        bf16x8 kfd = *(const bf16x8*)(kb + (size_t)(mb + 48 + lr) * DK_SZ + lk * 8);
        f32x4 s0 = mfma16(kfa, qf, (f32x4){0.f, 0.f, 0.f, 0.f});
        f32x4 s1 = mfma16(kfb, qf, (f32x4){0.f, 0.f, 0.f, 0.f});
        f32x4 s2 = mfma16(kfc, qf, (f32x4){0.f, 0.f, 0.f, 0.f});
        f32x4 s3 = mfma16(kfd, qf, (f32x4){0.f, 0.f, 0.f, 0.f});
#pragma unroll
        for (int r = 0; r < 4; r++)
            rs += __expf(s0[r]) + __expf(s1[r]) + __expf(s2[r]) + __expf(s3[r]);
    }
    rs += __shfl_xor(rs, 16);
    rs += __shfl_xor(rs, 32);
    if (l < 16) rsum_s[ch][rg * 16 + l] = rs;
    __syncthreads();
    const float invp = 1.f / (rsum_s[0][rg * 16 + lr] + rsum_s[1][rg * 16 + lr]);

    // ---- pass 2 ----
    float* attn_b = out + (size_t)B_SZ * C_SZ * N_SZ + (size_t)b * N_SZ * N_SZ;
    f32x4 O[4][4];   // O[cf][rgi]: c = rg*64+cf*16+4lk+r, n = rgi*16+lr (m-half partial)
#pragma unroll
    for (int cf = 0; cf < 4; cf++)
#pragma unroll
        for (int rgi = 0; rgi < 4; rgi++) O[cf][rgi] = (f32x4){0.f, 0.f, 0.f, 0.f};

    const int krow = ch * 32 + lr;
    const int kswz = ((lk ^ ((lr >> 1) & 3)) << 4);
    // PV A-frag offset within v_lds tile: c = rg*64 + cf*16 + lr, m-chunk = ch*4+lk
    const int aoff = rg * 8192 + lr * 128 + ((((ch << 2) + lk) ^ (lr & 7)) << 4);
    // PV B-frag byte offset within p_lds tile: row rgi*16+lr, m = ch*32+lk*8
    const int boff = lr * 144 + ch * 64 + lk * 16;

    bf16x8 kf0, kf1;

#define STAGE(tt, buf)                                                              \
    {                                                                               \
        const int krw = w * 8 + (l >> 2);                                           \
        const int ksl = (l & 3) ^ ((l >> 3) & 3);                                   \
        gload_lds16(kbb + (size_t)(tt) * 4096 + krw * 64 + ksl * 16,                \
                    (void*)&k_lds[buf][w * 256]);                                   \
        const int mb = (tt) * 64;                                                   \
        _Pragma("unroll")                                                           \
        for (int i = 0; i < 4; i++) {                                               \
            int c = w * 32 + i * 8 + (l >> 3);                                      \
            int j = l & 7;                                                          \
            const short* gp = vb + (size_t)c * N_SZ + mb + ((j ^ (c & 7)) << 3);    \
            gload_lds16(gp, (void*)&v_lds[buf][(w * 32 + i * 8) * 64]);             \
        }                                                                           \
    }

#define KREAD(tt)                                                                   \
    {                                                                               \
        const char* kl = (const char*)&k_lds[(tt) % 3][0];                          \
        kf0 = *(const bf16x8*)(kl + krow * 64 + kswz);                              \
        kf1 = *(const bf16x8*)(kl + krow * 64 + 1024 + kswz);                       \
    }

    // SCOMP(tt): S = mfma(K,Q); e = exp*inv; cvt; P -> p_lds[pb]. (no stores here)
#define SCOMP_BODY(tt, pb)                                                          \
    {                                                                               \
        f32x4 s0 = mfma16(kf0, qf, (f32x4){0.f, 0.f, 0.f, 0.f});                    \
        f32x4 s1 = mfma16(kf1, qf, (f32x4){0.f, 0.f, 0.f, 0.f});                    \
        float e00 = __expf(s0[0]) * invp, e01 = __expf(s0[1]) * invp;               \
        float e02 = __expf(s0[2]) * invp, e03 = __expf(s0[3]) * invp;               \
        float e10 = __expf(s1[0]) * invp, e11 = __expf(s1[1]) * invp;               \
        float e12 = __expf(s1[2]) * invp, e13 = __expf(s1[3]) * invp;               \
        u32x2 pk0, pk1;                                                             \
        pk0[0] = cvt_pk_bf16(e00, e01); pk0[1] = cvt_pk_bf16(e02, e03);             \
        pk1[0] = cvt_pk_bf16(e10, e11); pk1[1] = cvt_pk_bf16(e12, e13);             \
        *(u32x2*)(&p_lds[pb][rg * 16 + lr][ch * 32 + lk * 4]) = pk0;                \
        *(u32x2*)(&p_lds[pb][rg * 16 + lr][ch * 32 + 16 + lk * 4]) = pk1;           \
    }

    // ASTORE(tt): attention tile tt from p_lds[tt&1], FULL-LINE nt stores.
    // lane l of wave w -> row w*8+(l>>3), cols (l&7)*4 (+32): each 8-lane
    // group writes one aligned 128 B line per instruction.
#define ASTORE(tt)                                                                  \
    {                                                                               \
        const int arow = w * 8 + (l >> 3);                                          \
        const char* pr = (const char*)&p_lds[(tt) & 1][arow][0];                    \
        u32x2 u0 = *(const u32x2*)(pr + (l & 7) * 8);                               \
        u32x2 u1 = *(const u32x2*)(pr + 64 + (l & 7) * 8);                          \
        f32x4 f0, f1;                                                               \
        f0[0] = asf(u0[0] << 16); f0[1] = asf(u0[0] & 0xffff0000u);                 \
        f0[2] = asf(u0[1] << 16); f0[3] = asf(u0[1] & 0xffff0000u);                 \
        f1[0] = asf(u1[0] << 16); f1[1] = asf(u1[0] & 0xffff0000u);                 \
        f1[2] = asf(u1[1] << 16); f1[3] = asf(u1[1] & 0xffff0000u);                 \
        float* dst = attn_b + (size_t)(n0 + arow) * N_SZ + (tt) * 64 + (l & 7) * 4; \
        __builtin_nontemporal_store(f0, (f32x4*)dst);                               \
        __builtin_nontemporal_store(f1, (f32x4*)(dst + 32));                        \
    }

    // prologue
    STAGE(0, 0);
    STAGE(1, 1);
    __builtin_amdgcn_sched_barrier(0);
    asm volatile("s_waitcnt vmcnt(5)" ::: "memory");   // stage(0) landed
    __builtin_amdgcn_sched_barrier(0);
    __builtin_amdgcn_s_barrier();
    KREAD(0);
    SCOMP_BODY(0, 0);

    for (int mt = 0; mt < 64; mt++) {
        asm volatile("s_waitcnt vmcnt(2) lgkmcnt(0)" ::: "memory");
        __builtin_amdgcn_sched_barrier(0);
        __builtin_amdgcn_s_barrier();
        __builtin_amdgcn_sched_barrier(0);
        const int cur = mt & 1;
        if (mt < 63) KREAD(mt + 1);
        if (mt < 62) STAGE(mt + 2, (mt + 2) % 3);
        __builtin_amdgcn_sched_barrier(0);
        if (mt < 63) SCOMP_BODY(mt + 1, cur ^ 1);
        __builtin_amdgcn_sched_barrier(0);
        ASTORE(mt);
        __builtin_amdgcn_sched_barrier(0);
        // PV(mt): O[c = cq-quarter][n = all 64] += V-frags(1x read) * P-frags
        const char* vbase = (const char*)&v_lds[mt % 3][0];
        const char* pbase = (const char*)&p_lds[cur][0][0];
        bf16x8 Afr[4], Bfr[4];
#pragma unroll
        for (int cf = 0; cf < 4; cf++)
            Afr[cf] = *(const bf16x8*)(vbase + cf * 2048 + aoff);
#pragma unroll
        for (int rgi = 0; rgi < 4; rgi++)
            Bfr[rgi] = *(const bf16x8*)(pbase + rgi * 2304 + boff);
#pragma unroll
        for (int cf = 0; cf < 4; cf++)
#pragma unroll
            for (int rgi = 0; rgi < 4; rgi++)
                O[cf][rgi] = mfma16(Afr[cf], Bfr[rgi], O[cf][rgi]);
    }
#undef STAGE
#undef KREAD
#undef SCOMP_BODY
#undef ASTORE

    // ---- epilogue: reduce mh-pairs through LDS, then out = gamma*O + x ----
    __syncthreads();
    float* o_red = (float*)&v_lds[0][0];     // [4 n-grp][256 c][16 n], c-stride 17
    const int RSTRIDE = 4360;
    if (ch == 1) {
#pragma unroll
        for (int cf = 0; cf < 4; cf++)
#pragma unroll
            for (int rgi = 0; rgi < 4; rgi++)
#pragma unroll
                for (int r = 0; r < 4; r++)
                    o_red[rgi * RSTRIDE + (rg * 64 + cf * 16 + 4 * lk + r) * 17 + lr] = O[cf][rgi][r];
    }
    __syncthreads();
    if (ch == 0) {
#pragma unroll
        for (int cf = 0; cf < 4; cf++)
#pragma unroll
            for (int rgi = 0; rgi < 4; rgi++)
#pragma unroll
                for (int r = 0; r < 4; r++) {
                    int idx = rgi * RSTRIDE + (rg * 64 + cf * 16 + 4 * lk + r) * 17 + lr;
                    o_red[idx] += O[cf][rgi][r];
                }
    }
    __syncthreads();
    {
        const float g = gamma_p[0];
        const float* xb = x + (size_t)b * C_SZ * N_SZ;
        float* ob = out + (size_t)b * C_SZ * N_SZ;
        int nn = t & 63;
        int c0 = t >> 6;   // 0..7
        int rbase = (nn >> 4) * RSTRIDE + (nn & 15);
#pragma unroll
        for (int i = 0; i < 32; i++) {
            int c = c0 + 8 * i;
            size_t idx = (size_t)c * N_SZ + n0 + nn;
            ob[idx] = g * o_red[rbase + c * 17] + xb[idx];
        }
    }
}

extern "C" void kernel_launch(void* const* d_in, const int* in_sizes, int n_in,
                              void* d_out, int out_size, void* d_ws, size_t ws_size,
                              hipStream_t stream) {
    const float* x     = (const float*)d_in[0];
    const float* Wq    = (const float*)d_in[1];
    const float* bq    = (const float*)d_in[2];
    const float* Wk    = (const float*)d_in[3];
    const float* bk    = (const float*)d_in[4];
    const float* Wv    = (const float*)d_in[5];
    const float* bv    = (const float*)d_in[6];
    const float* gamma = (const float*)d_in[7];
    short* ws = (short*)d_ws;
    float* out = (float*)d_out;

    hipLaunchKernelGGL(k_convw, dim3(256), dim3(256), 0, stream, Wq, Wk, Wv, ws);
    hipLaunchKernelGGL(k_prep, dim3(256), dim3(256), 0, stream, x, bq, bk, bv, ws);
    hipLaunchKernelGGL(k_attn, dim3(256), dim3(512), 0, stream, ws, x, gamma, out);
}